// Round 4
// baseline (507.746 us; speedup 1.0000x reference)
//
#include <hip/hip_runtime.h>
#include <hip/hip_bf16.h>

#define NSITES 4096
#define TOTAL_READS 131072
#define C_IN 12
#define LLEN 32
#define NF 32
#define KSZ 5
#define NCLS 3
#define RPB 16                // reads per block
#define ROWE 24               // elements per xT row (48 B: 16 used + 8 pad for bank spread)
#define NROW 38               // rows per read: pos+kt in [0,36] + 1 pad
#define RDE (NROW * ROWE)     // 912 elements per read region

// ws layout:
//   off : int[2][NSITES+1]  at byte 0
//   r   : float[NSITES][2*NF] at byte OFF_R
#define OFF_R (64 * 1024)

typedef __attribute__((ext_vector_type(8))) short short8v;
typedef __attribute__((ext_vector_type(4))) float float4v;

__device__ __forceinline__ unsigned short f2bf(float x) {
    union { float f; unsigned u; } v; v.f = x;
    unsigned r = (v.u + 0x7FFFu + ((v.u >> 16) & 1u)) >> 16;
    return (unsigned short)r;
}

// ---------------- K0: prefix scan of counts -> offsets ----------------
__global__ void scan_kernel(const int* __restrict__ counts, int* __restrict__ off) {
    __shared__ int part[256];
    int t = threadIdx.x;
    for (int row = 0; row < 2; ++row) {
        const int* c = counts + row * NSITES;
        int* o = off + row * (NSITES + 1);
        int local[16];
        int sum = 0;
#pragma unroll
        for (int i = 0; i < 16; ++i) { local[i] = sum; sum += c[t * 16 + i]; }
        part[t] = sum;
        __syncthreads();
        for (int d = 1; d < 256; d <<= 1) {
            int v = (t >= d) ? part[t - d] : 0;
            __syncthreads();
            part[t] += v;
            __syncthreads();
        }
        int base = (t == 0) ? 0 : part[t - 1];
#pragma unroll
        for (int i = 0; i < 16; ++i) o[t * 16 + i] = base + local[i];
        if (t == 0) o[NSITES] = TOTAL_READS;
        __syncthreads();
    }
}

// ---------------- K1: bf16-MFMA conv via pos-major LDS + wide reads ------
// xT layout per read: row = pos+kt in [0,37], 24 elems/row (48 B), elems
// 0..11 = channels, 12..15 zero, 16..23 unread pad. A-fragment for MFMA
// k-slot (q,j): kt = 2*kk + (q>>1), c = (q&1)*8 + j  -> one ds_read_b128
// per (mi,kk) at row (mi*16 + r16 + (q>>1) + 2*kk), byte offset (q&1)*16.
// B (weights) uses the SAME logical k-map with zeros for kt>=5 / c>=12;
// A/B k-permutation symmetry is HW-validated (round 3, absmax 3.9e-3).
__global__ __launch_bounds__(256, 4) void feat_kernel(
    const float* __restrict__ x0, const float* __restrict__ x1,
    const float* __restrict__ W0, const float* __restrict__ b0,
    const float* __restrict__ W1, const float* __restrict__ b1,
    const int* __restrict__ off, float* __restrict__ r) {

    __shared__ unsigned short xl[RPB * RDE];   // 29184 B
    __shared__ float bl[NF];
    __shared__ int   sites[RPB];

    const int blk = blockIdx.x;
    const int input = (blk >= (TOTAL_READS / RPB)) ? 1 : 0;
    const int rbase = (blk - input * (TOTAL_READS / RPB)) * RPB;
    const float* __restrict__ x  = input ? x1 : x0;
    const float* __restrict__ Wg = input ? W1 : W0;
    const float* __restrict__ bg = input ? b1 : b0;
    const int* __restrict__ orow = off + input * (NSITES + 1);

    const int t = threadIdx.x;
    const int lane = t & 63;
    const int wave = t >> 6;
    const int r16 = lane & 15;
    const int hi  = lane >> 4;

    // ---- B fragments (weights) in registers: bfrag[ni][kk]
    // slot (q=hi, j): kt = 2*kk + (hi>>1), c = (hi&1)*8 + j
    short8v bfrag[2][3];
#pragma unroll
    for (int ni = 0; ni < 2; ++ni)
#pragma unroll
        for (int kk = 0; kk < 3; ++kk) {
            union { short8v v; unsigned short u[8]; } tmp;
            const int kt = 2 * kk + (hi >> 1);
#pragma unroll
            for (int j = 0; j < 8; ++j) {
                const int c = (hi & 1) * 8 + j;
                const int f = ni * 16 + r16;
                float w = (kt < KSZ && c < C_IN) ? Wg[f * 60 + c * 5 + kt] : 0.f;
                tmp.u[j] = f2bf(w);
            }
            bfrag[ni][kk] = tmp.v;
        }

    // ---- zero dead LDS slots (disjoint from data writes -> no extra barrier)
    // rows {0,1,34,35,36,37} fully; elems 12..15 of rows 2..33
    for (int i = t; i < RPB * 18; i += 256) {          // 288 float4 row-chunks
        const int rd = i / 18, rem = i % 18;
        const int idx = rem / 3, chunk = rem % 3;
        const int row = (idx < 2) ? idx : idx + 32;    // 0,1,34,35,36,37
        float4 z = {0.f, 0.f, 0.f, 0.f};
        *(float4*)&xl[rd * RDE + row * ROWE + chunk * 8] = z;
    }
    for (int i = t; i < RPB * 32; i += 256) {          // 512 u64 c-pad zeros
        const int rd = i / 32, row = 2 + (i % 32);
        *(unsigned long long*)&xl[rd * RDE + row * ROWE + 12] = 0ull;
    }

    // ---- stage x -> xT in LDS via 4x4 register transpose
    // unit u = (rr, ciq, posq): load x[rr][ciq*4+k][posq*4..+3], write
    // 4 pos-rows of 4 channels each as ds_write_b64.
#pragma unroll
    for (int uu = 0; uu < 2; ++uu) {
        const int u = t + uu * 256;
        if (u < RPB * 24) {
            const int rr = u / 24, rem = u % 24;
            const int ciq = rem >> 3, posq = rem & 7;
            const float* xg = x + (size_t)(rbase + rr) * (C_IN * LLEN)
                              + (ciq * 4) * LLEN + posq * 4;
            float4 q0 = *(const float4*)(xg);
            float4 q1 = *(const float4*)(xg + LLEN);
            float4 q2 = *(const float4*)(xg + 2 * LLEN);
            float4 q3 = *(const float4*)(xg + 3 * LLEN);
            const float* a0 = (const float*)&q0;
            const float* a1 = (const float*)&q1;
            const float* a2 = (const float*)&q2;
            const float* a3 = (const float*)&q3;
#pragma unroll
            for (int p = 0; p < 4; ++p) {
                unsigned long long w =
                      (unsigned long long)f2bf(a0[p])
                    | ((unsigned long long)f2bf(a1[p]) << 16)
                    | ((unsigned long long)f2bf(a2[p]) << 32)
                    | ((unsigned long long)f2bf(a3[p]) << 48);
                const int row = posq * 4 + p + 2;      // pos + 2
                *(unsigned long long*)&xl[rr * RDE + row * ROWE + ciq * 4] = w;
            }
        }
    }

    if (t < NF) bl[t] = bg[t];
    if (t < RPB) {
        int n = rbase + t;
        int lo = 0, hq = NSITES;
        while (hq - lo > 1) { int mid = (lo + hq) >> 1; if (orow[mid] <= n) lo = mid; else hq = mid; }
        sites[t] = lo;
    }
    __syncthreads();

    const float bias0 = bl[r16];
    const float bias1 = bl[16 + r16];
    const int arow = r16 + (hi >> 1);      // row base within (rd, mi)
    const int acol = (hi & 1) * 8;         // element offset within row

#pragma unroll
    for (int ri = 0; ri < RPB / 4; ++ri) {
        const int rd = wave * (RPB / 4) + ri;

        float4v acc[2][2];
#pragma unroll
        for (int mi = 0; mi < 2; ++mi)
#pragma unroll
            for (int ni = 0; ni < 2; ++ni) {
                float4v z = {0.f, 0.f, 0.f, 0.f};
                acc[mi][ni] = z;
            }

#pragma unroll
        for (int mi = 0; mi < 2; ++mi) {
            const unsigned short* xr = &xl[rd * RDE + (mi * 16 + arow) * ROWE + acol];
#pragma unroll
            for (int kk = 0; kk < 3; ++kk) {
                const short8v a = *(const short8v*)(xr + kk * 2 * ROWE);
#pragma unroll
                for (int ni = 0; ni < 2; ++ni)
                    acc[mi][ni] = __builtin_amdgcn_mfma_f32_16x16x32_bf16(
                        a, bfrag[ni][kk], acc[mi][ni], 0, 0, 0);
            }
        }

        // epilogue: relu(y+b), mean over 32 pos, ragged atomic pool.
        // C/D layout: col = lane&15, row = (lane>>4)*4 + reg (HW-verified).
        float p0 = 0.f, p1 = 0.f;
#pragma unroll
        for (int mi = 0; mi < 2; ++mi)
#pragma unroll
            for (int q = 0; q < 4; ++q) {
                p0 += fmaxf(acc[mi][0][q] + bias0, 0.f);
                p1 += fmaxf(acc[mi][1][q] + bias1, 0.f);
            }
        p0 += __shfl_xor(p0, 16, 64); p0 += __shfl_xor(p0, 32, 64);
        p1 += __shfl_xor(p1, 16, 64); p1 += __shfl_xor(p1, 32, 64);
        if (hi == 0) {
            const int s = sites[rd];
            atomicAdd(&r[s * (2 * NF) + input * NF + r16],      p0 * (1.f / 32.f));
            atomicAdd(&r[s * (2 * NF) + input * NF + 16 + r16], p1 * (1.f / 32.f));
        }
    }
}

// ---------------- K2: site combiner + softmax ----------------
__global__ void comb_kernel(const float* __restrict__ r, const float* __restrict__ W2,
                            const float* __restrict__ b2, float* __restrict__ out) {
    int s = blockIdx.x * blockDim.x + threadIdx.x;
    if (s >= NSITES) return;
    const float4* rv = (const float4*)(r + (size_t)s * (2 * NF));
    float acc[NCLS];
#pragma unroll
    for (int j = 0; j < NCLS; ++j) acc[j] = b2[j];
#pragma unroll
    for (int v = 0; v < 16; ++v) {
        float4 q = rv[v];
#pragma unroll
        for (int j = 0; j < NCLS; ++j) {
            float4 wq = ((const float4*)(W2 + j * 2 * NF))[v];
            acc[j] += q.x * wq.x + q.y * wq.y + q.z * wq.z + q.w * wq.w;
        }
    }
    float m = fmaxf(acc[0], fmaxf(acc[1], acc[2]));
    float e0 = __expf(acc[0] - m), e1 = __expf(acc[1] - m), e2 = __expf(acc[2] - m);
    float inv = 1.f / (e0 + e1 + e2);
    out[s * 3 + 0] = e0 * inv;
    out[s * 3 + 1] = e1 * inv;
    out[s * 3 + 2] = e2 * inv;
}

extern "C" void kernel_launch(void* const* d_in, const int* in_sizes, int n_in,
                              void* d_out, int out_size, void* d_ws, size_t ws_size,
                              hipStream_t stream) {
    const float* x0 = (const float*)d_in[0];
    const float* x1 = (const float*)d_in[1];
    const int* counts = (const int*)d_in[2];
    const float* W0 = (const float*)d_in[3];
    const float* b0 = (const float*)d_in[4];
    const float* W1 = (const float*)d_in[5];
    const float* b1 = (const float*)d_in[6];
    const float* W2 = (const float*)d_in[7];
    const float* b2 = (const float*)d_in[8];
    float* out = (float*)d_out;

    int* off = (int*)d_ws;
    float* r = (float*)((char*)d_ws + OFF_R);

    hipMemsetAsync(r, 0, (size_t)NSITES * 2 * NF * sizeof(float), stream);
    scan_kernel<<<1, 256, 0, stream>>>(counts, off);
    feat_kernel<<<2 * (TOTAL_READS / RPB), 256, 0, stream>>>(x0, x1, W0, b0, W1, b1, off, r);
    comb_kernel<<<(NSITES + 255) / 256, 256, 0, stream>>>(r, W2, b2, out);
}

// Round 5
// 500.099 us; speedup vs baseline: 1.0153x; 1.0153x over previous
//
#include <hip/hip_runtime.h>
#include <hip/hip_bf16.h>

#define NSITES 4096
#define TOTAL_READS 131072
#define C_IN 12
#define LLEN 32
#define NF 32
#define KSZ 5
#define NCLS 3
#define RPB 8                 // reads per tile
#define NT 32                 // tiles per block (persistent)
#define ROWE 28               // elems per xT row (56 B: uniform bank coverage mod 128)
#define NROW 38               // rows: pos+kt in [0,36] + 1 pad
#define RDE (NROW * ROWE)     // 1064 elems per read region

// ws layout:
//   off : int[2][NSITES+1]  at byte 0
//   r   : float[NSITES][2*NF] at byte OFF_R
#define OFF_R (64 * 1024)

typedef __attribute__((ext_vector_type(8))) short short8v;
typedef __attribute__((ext_vector_type(4))) float float4v;

__device__ __forceinline__ unsigned short f2bf(float x) {
    union { float f; unsigned u; } v; v.f = x;
    unsigned r = (v.u + 0x7FFFu + ((v.u >> 16) & 1u)) >> 16;
    return (unsigned short)r;
}

// ---------------- K0: prefix scan of counts -> offsets ----------------
__global__ void scan_kernel(const int* __restrict__ counts, int* __restrict__ off) {
    __shared__ int part[256];
    int t = threadIdx.x;
    for (int row = 0; row < 2; ++row) {
        const int* c = counts + row * NSITES;
        int* o = off + row * (NSITES + 1);
        int local[16];
        int sum = 0;
#pragma unroll
        for (int i = 0; i < 16; ++i) { local[i] = sum; sum += c[t * 16 + i]; }
        part[t] = sum;
        __syncthreads();
        for (int d = 1; d < 256; d <<= 1) {
            int v = (t >= d) ? part[t - d] : 0;
            __syncthreads();
            part[t] += v;
            __syncthreads();
        }
        int base = (t == 0) ? 0 : part[t - 1];
#pragma unroll
        for (int i = 0; i < 16; ++i) o[t * 16 + i] = base + local[i];
        if (t == 0) o[NSITES] = TOTAL_READS;
        __syncthreads();
    }
}

// ---------------- K1: persistent double-buffered bf16-MFMA conv ----------
// 1024 blocks (4/CU, fully resident), 32 tiles x 8 reads each.
// Pipeline per tile: issue loads(t+1) at TOP (barrier never drains them),
// compute buf[t&1], convert+write regs -> buf[(t+1)&1], one barrier.
// A/B k-map (HW-validated r3/r4): slot(q=hi,j): kt=2kk+(hi>>1), c=(hi&1)*8+j.
__global__ __launch_bounds__(256, 4) void feat_kernel(
    const float* __restrict__ x0, const float* __restrict__ x1,
    const float* __restrict__ W0, const float* __restrict__ b0,
    const float* __restrict__ W1, const float* __restrict__ b1,
    const int* __restrict__ off, float* __restrict__ r) {

    __shared__ unsigned short xl[2][RPB * RDE];   // 34048 B
    __shared__ float bl[NF];
    __shared__ int   sites[2][RPB];

    const int b = blockIdx.x;
    const int input = b >> 9;                      // 512 blocks per input
    const int rbase0 = (b & 511) * (NT * RPB);     // 256 reads per block
    const float* __restrict__ x  = input ? x1 : x0;
    const float* __restrict__ Wg = input ? W1 : W0;
    const float* __restrict__ bg = input ? b1 : b0;
    const int* __restrict__ orow = off + input * (NSITES + 1);

    const int t = threadIdx.x;
    const int lane = t & 63;
    const int wave = t >> 6;
    const int r16 = lane & 15;
    const int hi  = lane >> 4;

    // ---- B fragments (weights), once per block
    short8v bfrag[2][3];
#pragma unroll
    for (int ni = 0; ni < 2; ++ni)
#pragma unroll
        for (int kk = 0; kk < 3; ++kk) {
            union { short8v v; unsigned short u[8]; } tmp;
            const int kt = 2 * kk + (hi >> 1);
#pragma unroll
            for (int j = 0; j < 8; ++j) {
                const int c = (hi & 1) * 8 + j;
                const int f = ni * 16 + r16;
                float w = (kt < KSZ && c < C_IN) ? Wg[f * 60 + c * 5 + kt] : 0.f;
                tmp.u[j] = f2bf(w);
            }
            bfrag[ni][kk] = tmp.v;
        }

    if (t < NF) bl[t] = bg[t];

    // ---- zero both buffers once (pad slots persist; data rewritten per tile)
    {
        unsigned long long* z = (unsigned long long*)&xl[0][0];
        for (int i = t; i < 2 * RPB * RDE / 4; i += 256) z[i] = 0ull;
    }
    __syncthreads();   // zeros visible before any data write

    // ---- stager geometry: 192 threads, unit = (rr, ciq, posq) 4c x 4pos
    const bool stager = (t < 192);
    const int rr   = t / 24;
    const int rem  = t % 24;
    const int ciq  = rem >> 3;
    const int posq = rem & 7;

    float4 q0, q1, q2, q3;

#define ISSUE(tile) do { if (stager) {                                          \
        const float* g = x + (size_t)(rbase0 + (tile) * RPB + rr) * (C_IN*LLEN) \
                           + (ciq * 4) * LLEN + posq * 4;                       \
        q0 = *(const float4*)(g);                                               \
        q1 = *(const float4*)(g + LLEN);                                        \
        q2 = *(const float4*)(g + 2 * LLEN);                                    \
        q3 = *(const float4*)(g + 3 * LLEN); } } while (0)

#define SITESRCH(tile, buf) do { if (t >= 192 && t < 192 + RPB) {               \
        int n = rbase0 + (tile) * RPB + (t - 192);                              \
        int lo = 0, hq = NSITES;                                                \
        while (hq - lo > 1) { int mid = (lo + hq) >> 1;                         \
            if (orow[mid] <= n) lo = mid; else hq = mid; }                      \
        sites[buf][t - 192] = lo; } } while (0)

#define WRITE(buf) do { if (stager) {                                           \
        const float* a0 = (const float*)&q0;                                    \
        const float* a1 = (const float*)&q1;                                    \
        const float* a2 = (const float*)&q2;                                    \
        const float* a3 = (const float*)&q3;                                    \
        _Pragma("unroll")                                                       \
        for (int p = 0; p < 4; ++p) {                                           \
            unsigned long long w =                                              \
                  (unsigned long long)f2bf(a0[p])                               \
                | ((unsigned long long)f2bf(a1[p]) << 16)                       \
                | ((unsigned long long)f2bf(a2[p]) << 32)                       \
                | ((unsigned long long)f2bf(a3[p]) << 48);                      \
            *(unsigned long long*)&xl[buf][rr * RDE + (posq * 4 + p + 2) * ROWE \
                                           + ciq * 4] = w; } } } while (0)

    // ---- prologue: tile 0 into buf 0
    ISSUE(0);
    SITESRCH(0, 0);
    WRITE(0);
    __syncthreads();

    const float bias0 = bl[r16];
    const float bias1 = bl[16 + r16];
    const int arow = r16 + (hi >> 1);
    const int acol = (hi & 1) * 8;

#pragma unroll 2
    for (int tt = 0; tt < NT; ++tt) {
        const int cur = tt & 1;
        if (tt + 1 < NT) { ISSUE(tt + 1); SITESRCH(tt + 1, cur ^ 1); }

        // ---- compute tile tt from xl[cur]
#pragma unroll
        for (int ri = 0; ri < 2; ++ri) {
            const int rd = wave * 2 + ri;

            float4v acc[2][2];
#pragma unroll
            for (int mi = 0; mi < 2; ++mi)
#pragma unroll
                for (int ni = 0; ni < 2; ++ni) {
                    float4v z = {0.f, 0.f, 0.f, 0.f};
                    acc[mi][ni] = z;
                }

#pragma unroll
            for (int mi = 0; mi < 2; ++mi) {
                const unsigned short* xr =
                    &xl[cur][rd * RDE + (mi * 16 + arow) * ROWE + acol];
#pragma unroll
                for (int kk = 0; kk < 3; ++kk) {
                    const short8v a = *(const short8v*)(xr + kk * 2 * ROWE);
#pragma unroll
                    for (int ni = 0; ni < 2; ++ni)
                        acc[mi][ni] = __builtin_amdgcn_mfma_f32_16x16x32_bf16(
                            a, bfrag[ni][kk], acc[mi][ni], 0, 0, 0);
                }
            }

            // epilogue: relu(y+b), mean over 32 pos, ragged atomic pool.
            // C/D layout: col = lane&15, row = (lane>>4)*4 + reg (HW-verified).
            float p0 = 0.f, p1 = 0.f;
#pragma unroll
            for (int mi = 0; mi < 2; ++mi)
#pragma unroll
                for (int q = 0; q < 4; ++q) {
                    p0 += fmaxf(acc[mi][0][q] + bias0, 0.f);
                    p1 += fmaxf(acc[mi][1][q] + bias1, 0.f);
                }
            p0 += __shfl_xor(p0, 16, 64); p0 += __shfl_xor(p0, 32, 64);
            p1 += __shfl_xor(p1, 16, 64); p1 += __shfl_xor(p1, 32, 64);
            if (hi == 0) {
                const int s = sites[cur][rd];
                atomicAdd(&r[s * (2 * NF) + input * NF + r16],      p0 * (1.f / 32.f));
                atomicAdd(&r[s * (2 * NF) + input * NF + 16 + r16], p1 * (1.f / 32.f));
            }
        }

        if (tt + 1 < NT) WRITE(cur ^ 1);   // regs landed during compute
        __syncthreads();
    }
#undef ISSUE
#undef SITESRCH
#undef WRITE
}

// ---------------- K2: site combiner + softmax ----------------
__global__ void comb_kernel(const float* __restrict__ r, const float* __restrict__ W2,
                            const float* __restrict__ b2, float* __restrict__ out) {
    int s = blockIdx.x * blockDim.x + threadIdx.x;
    if (s >= NSITES) return;
    const float4* rv = (const float4*)(r + (size_t)s * (2 * NF));
    float acc[NCLS];
#pragma unroll
    for (int j = 0; j < NCLS; ++j) acc[j] = b2[j];
#pragma unroll
    for (int v = 0; v < 16; ++v) {
        float4 q = rv[v];
#pragma unroll
        for (int j = 0; j < NCLS; ++j) {
            float4 wq = ((const float4*)(W2 + j * 2 * NF))[v];
            acc[j] += q.x * wq.x + q.y * wq.y + q.z * wq.z + q.w * wq.w;
        }
    }
    float m = fmaxf(acc[0], fmaxf(acc[1], acc[2]));
    float e0 = __expf(acc[0] - m), e1 = __expf(acc[1] - m), e2 = __expf(acc[2] - m);
    float inv = 1.f / (e0 + e1 + e2);
    out[s * 3 + 0] = e0 * inv;
    out[s * 3 + 1] = e1 * inv;
    out[s * 3 + 2] = e2 * inv;
}

extern "C" void kernel_launch(void* const* d_in, const int* in_sizes, int n_in,
                              void* d_out, int out_size, void* d_ws, size_t ws_size,
                              hipStream_t stream) {
    const float* x0 = (const float*)d_in[0];
    const float* x1 = (const float*)d_in[1];
    const int* counts = (const int*)d_in[2];
    const float* W0 = (const float*)d_in[3];
    const float* b0 = (const float*)d_in[4];
    const float* W1 = (const float*)d_in[5];
    const float* b1 = (const float*)d_in[6];
    const float* W2 = (const float*)d_in[7];
    const float* b2 = (const float*)d_in[8];
    float* out = (float*)d_out;

    int* off = (int*)d_ws;
    float* r = (float*)((char*)d_ws + OFF_R);

    hipMemsetAsync(r, 0, (size_t)NSITES * 2 * NF * sizeof(float), stream);
    scan_kernel<<<1, 256, 0, stream>>>(counts, off);
    feat_kernel<<<1024, 256, 0, stream>>>(x0, x1, W0, b0, W1, b1, off, r);
    comb_kernel<<<(NSITES + 255) / 256, 256, 0, stream>>>(r, W2, b2, out);
}